// Round 11
// baseline (332.054 us; speedup 1.0000x reference)
//
#include <hip/hip_runtime.h>
#include <hip/hip_bf16.h>

// Problem constants (from reference)
#define N_NODES 50000
#define N_EDGES 400000
#define EP (N_EDGES + N_NODES)   // edges incl. self loops = 450000
#define IN_F 128
#define H_HEADS 8
#define C_CH 32
#define HC 256                   // H*C
#define ED_F 16
#define NEG_SLOPE 0.2f
#define LN_EPS 1e-5f
#define NB_SCAN ((N_NODES + 2047) / 2048)   // 25 blocks in phase-A scan
#define NDBINS 1024
#define KF_NB 4096

typedef __hip_bfloat16 bf16;
typedef float v2f __attribute__((ext_vector_type(2)));
typedef short bf16x8 __attribute__((ext_vector_type(8)));
typedef float f32x4 __attribute__((ext_vector_type(4)));
typedef _Float16 h2f __attribute__((ext_vector_type(2)));

__device__ __forceinline__ float bfu(unsigned short v){
    return __uint_as_float((unsigned int)v << 16);
}
__device__ __forceinline__ unsigned short f2b(float v){
    bf16 t = __float2bfloat16(v);
    return *reinterpret_cast<unsigned short*>(&t);
}
__device__ __forceinline__ h2f u2h(unsigned int u){
    union { unsigned int u; h2f h; } x; x.u = u; return x.h;
}

// ---------------- combined input casts / weight prep / degree count (one kernel) ----------------
#define CASTX_NB 3125
#define CASTE_NB 3125
#define W1_NB 128
#define W2_NB 32
#define DEG_NB ((N_EDGES + 255) / 256)
#define PREP_W_END (CASTX_NB + CASTE_NB + 2 * W1_NB + 2 * W2_NB)   // 6570

__device__ __forceinline__ void prepW_body(const float* __restrict__ W,
                                           unsigned short* __restrict__ Wt,
                                           int K, int idx){
    if (idx >= 256 * K) return;
    int c = idx & 255, k = idx >> 8;
    Wt[(size_t)c * K + k] = f2b(W[idx]);
}

__global__ void k_prep(const float* __restrict__ x, unsigned short* __restrict__ xb,
                       const float* __restrict__ ea, _Float16* __restrict__ eah,
                       const float* __restrict__ Wl1, unsigned short* __restrict__ Wt1l,
                       const float* __restrict__ Wr1, unsigned short* __restrict__ Wt1r,
                       const float* __restrict__ Wl2, unsigned short* __restrict__ Wt2l,
                       const float* __restrict__ Wr2, unsigned short* __restrict__ Wt2r,
                       const float* __restrict__ We1, _Float16* __restrict__ weh1T,
                       const float* __restrict__ We2, _Float16* __restrict__ weh2T,
                       const int* __restrict__ dstA, int* __restrict__ deg){
    int b = blockIdx.x, t = threadIdx.x;
    if (b < CASTX_NB){
        int i = b * 256 + t;
        if (i >= N_NODES * IN_F / 8) return;
        const float4* p = reinterpret_cast<const float4*>(x + (size_t)i * 8);
        float4 v0 = p[0], v1 = p[1];
        unsigned short o[8] = {f2b(v0.x), f2b(v0.y), f2b(v0.z), f2b(v0.w),
                               f2b(v1.x), f2b(v1.y), f2b(v1.z), f2b(v1.w)};
        *reinterpret_cast<uint4*>(xb + (size_t)i * 8) = *reinterpret_cast<uint4*>(o);
    } else if (b < CASTX_NB + CASTE_NB){
        int i = (b - CASTX_NB) * 256 + t;     // < 800000 exactly
        const float4* p = reinterpret_cast<const float4*>(ea + (size_t)i * 8);
        float4 v0 = p[0], v1 = p[1];
        _Float16 o[8] = {(_Float16)v0.x, (_Float16)v0.y, (_Float16)v0.z, (_Float16)v0.w,
                         (_Float16)v1.x, (_Float16)v1.y, (_Float16)v1.z, (_Float16)v1.w};
        *reinterpret_cast<uint4*>(eah + (size_t)i * 8) = *reinterpret_cast<uint4*>(o);
    } else if (b < CASTX_NB + CASTE_NB + W1_NB){
        prepW_body(Wl1, Wt1l, IN_F, (b - CASTX_NB - CASTE_NB) * 256 + t);
    } else if (b < CASTX_NB + CASTE_NB + 2 * W1_NB){
        prepW_body(Wr1, Wt1r, IN_F, (b - CASTX_NB - CASTE_NB - W1_NB) * 256 + t);
    } else if (b < CASTX_NB + CASTE_NB + 2 * W1_NB + W2_NB){
        prepW_body(Wl2, Wt2l, C_CH, (b - CASTX_NB - CASTE_NB - 2 * W1_NB) * 256 + t);
    } else if (b < PREP_W_END){
        prepW_body(Wr2, Wt2r, C_CH, (b - CASTX_NB - CASTE_NB - 2 * W1_NB - W2_NB) * 256 + t);
    } else if (b == PREP_W_END){
        // We1^T: weh1T[c][j] = We1[j][c], f16, 16 contiguous per channel
#pragma unroll
        for (int j = 0; j < ED_F; ++j)
            weh1T[t * ED_F + j] = (_Float16)We1[j * HC + t];
    } else if (b == PREP_W_END + 1){
#pragma unroll
        for (int j = 0; j < ED_F; ++j)
            weh2T[t * ED_F + j] = (_Float16)We2[j * HC + t];
    } else {
        // merged k_deg
        int e = (b - PREP_W_END - 2) * 256 + t;
        if (e < N_EDGES) atomicAdd(&deg[dstA[e]], 1);
    }
}

// ---------------- CSR build ----------------

// scanA + merged degree histogram: bin = NDBINS-1 - min(deg+1, NDBINS-1)
__global__ void k_scanA(const int* __restrict__ deg, int* __restrict__ ptr,
                        int* __restrict__ bsum, int* __restrict__ hist){
    __shared__ int wsum[4];
    __shared__ int lh[NDBINS];
    int blk = blockIdx.x;
    int base0 = blk * 2048;
    int t = threadIdx.x, lane = t & 63, wv = t >> 6;
    for (int j = t; j < NDBINS; j += 256) lh[j] = 0;
    __syncthreads();
    int carry = 0;
    for (int c = 0; c < 8; ++c){
        int i = base0 + c * 256 + t;
        int v = (i < N_NODES) ? (deg[i] + 1) : 0;
        if (i < N_NODES) atomicAdd(&lh[NDBINS - 1 - min(v, NDBINS - 1)], 1);
        int x = v;
#pragma unroll
        for (int off = 1; off < 64; off <<= 1){
            int y = __shfl_up(x, off, 64);
            if (lane >= off) x += y;
        }
        if (lane == 63) wsum[wv] = x;
        __syncthreads();
        int pre = carry;
        for (int j = 0; j < wv; ++j) pre += wsum[j];
        if (i < N_NODES) ptr[i] = pre + x - v;
        int tot = wsum[0] + wsum[1] + wsum[2] + wsum[3];
        __syncthreads();
        carry += tot;
    }
    if (t == 0) bsum[blk] = carry;
    for (int j = t; j < NDBINS; j += 256)
        if (lh[j]) atomicAdd(&hist[j], lh[j]);
}

// merged scanB (boff over 25 block sums) + scanH (hoff over 1024 bins)
__global__ void k_scanBH(const int* __restrict__ bsum, int* __restrict__ boff,
                         const int* __restrict__ hist, int* __restrict__ hoff){
    __shared__ int wsum[4];
    __shared__ int carry_s;
    int t = threadIdx.x, lane = t & 63, wv = t >> 6;
    if (t == 0) carry_s = 0;
    __syncthreads();
    for (int base = 0; base < NDBINS; base += 256){
        int i = base + t;
        int v = hist[i];
        int x = v;
#pragma unroll
        for (int off = 1; off < 64; off <<= 1){
            int y = __shfl_up(x, off, 64);
            if (lane >= off) x += y;
        }
        if (lane == 63) wsum[wv] = x;
        __syncthreads();
        int pre = carry_s;
        for (int j = 0; j < wv; ++j) pre += wsum[j];
        hoff[i] = pre + x - v;
        int tot = wsum[0] + wsum[1] + wsum[2] + wsum[3];
        __syncthreads();
        if (t == 0) carry_s += tot;
        __syncthreads();
    }
    if (t < 64){
        int v = (t < NB_SCAN) ? bsum[t] : 0;
        int x = v;
#pragma unroll
        for (int off = 1; off < 64; off <<= 1){
            int y = __shfl_up(x, off, 64);
            if (t >= off) x += y;
        }
        if (t < NB_SCAN) boff[t] = x - v;
        if (t == 63) boff[NB_SCAN] = x;
    }
}

__global__ void k_scanC(int* __restrict__ ptr, const int* __restrict__ boff){
    int i = blockIdx.x * 256 + threadIdx.x;
    if (i < N_NODES) ptr[i] += boff[i >> 11];
    else if (i == N_NODES) ptr[i] = boff[NB_SCAN];
}

// scatter edges into CSR slots and emit (edge, src) pairs directly.
__global__ void k_scatter(const int* __restrict__ srcA, const int* __restrict__ dstA,
                          const int* __restrict__ ptr, int* __restrict__ cur,
                          int2* __restrict__ es){
    int e = blockIdx.x * 256 + threadIdx.x;
    if (e >= EP) return;
    int n, s;
    if (e < N_EDGES){ n = dstA[e]; s = srcA[e]; }
    else            { n = e - N_EDGES; s = n; }
    int p = ptr[n] + atomicAdd(&cur[n], 1);
    es[p] = make_int2(e, s);
}

__global__ void k_loopattr(const int* __restrict__ ptr, const int2* __restrict__ es,
                           const float* __restrict__ ea, const int* __restrict__ deg,
                           _Float16* __restrict__ lah){
    int idx = blockIdx.x * 256 + threadIdx.x;
    if (idx >= N_NODES * ED_F) return;
    int n = idx >> 4, j = idx & 15;
    float s = 0.f;
    int b = ptr[n], t = ptr[n + 1];
    for (int i = b; i < t; ++i){
        int e = es[i].x;
        if (e < N_EDGES) s += ea[(size_t)e * ED_F + j];
    }
    lah[idx] = (_Float16)(s / (float)max(deg[n], 1));
}

__global__ void k_place(const int* __restrict__ ptr, const int* __restrict__ hoff,
                        int* __restrict__ hcur, int* __restrict__ ord){
    __shared__ int lh[NDBINS];
    __shared__ int lbase[NDBINS];
    int t = threadIdx.x;
    for (int i = t; i < NDBINS; i += 256) lh[i] = 0;
    __syncthreads();
    int n = blockIdx.x * 256 + t;
    int b = -1, lr = 0;
    if (n < N_NODES){
        int d = min(ptr[n + 1] - ptr[n], NDBINS - 1);
        b = NDBINS - 1 - d;
        lr = atomicAdd(&lh[b], 1);
    }
    __syncthreads();
    for (int i = t; i < NDBINS; i += 256)
        if (lh[i]) lbase[i] = atomicAdd(&hcur[i], lh[i]);
    __syncthreads();
    if (n < N_NODES) ord[hoff[b] + lbase[b] + lr] = n;
}

// ---------------- MFMA pair GEMM: xl(bf16) = A@Wl + bl, xr(bf16) = A@Wr + br ----------------
// MERGED Wl/Wr: one block stages A once and computes BOTH weight products for
// its 128-column half (grid.y = 2, was 4). Halves A global traffic (was read
// 4x) and doubles MFMA per barrier pair (16 vs 8). LDS 25KB; 2x8 f32x4 acc.
template<int K>
__global__ __launch_bounds__(256)
void k_gemmM(const unsigned short* __restrict__ A,
             const unsigned short* __restrict__ Wtl, const float* __restrict__ bl,
             const unsigned short* __restrict__ Wtr, const float* __restrict__ br,
             bf16* __restrict__ xlh, unsigned short* __restrict__ xrh){
    const int c0 = blockIdx.y * 128;
    const int r0 = blockIdx.x * 64;

    __shared__ unsigned short sA[64][40];
    __shared__ unsigned short sL[128][40];
    __shared__ unsigned short sR[128][40];

    const int tid = threadIdx.x;
    const int lane = tid & 63;
    const int w = tid >> 6;

    f32x4 accL[8] = {};
    f32x4 accR[8] = {};

    for (int kt = 0; kt < K; kt += 32){
        {   // stage A: 64 rows x 32 k
            int row = tid >> 2, kc = (tid & 3) * 8;
            int gr = r0 + row;
            uint4 v = make_uint4(0, 0, 0, 0);
            if (gr < N_NODES)
                v = *reinterpret_cast<const uint4*>(&A[(size_t)gr * K + kt + kc]);
            *reinterpret_cast<uint4*>(&sA[row][kc]) = v;
        }
        {   // stage Wl and Wr: 128 cols x 32 k each
            int c = tid >> 1, kc = (tid & 1) * 16;
            const unsigned short* pl = &Wtl[(size_t)(c0 + c) * K + kt + kc];
            *reinterpret_cast<uint4*>(&sL[c][kc])     = *reinterpret_cast<const uint4*>(pl);
            *reinterpret_cast<uint4*>(&sL[c][kc + 8]) = *reinterpret_cast<const uint4*>(pl + 8);
            const unsigned short* pr = &Wtr[(size_t)(c0 + c) * K + kt + kc];
            *reinterpret_cast<uint4*>(&sR[c][kc])     = *reinterpret_cast<const uint4*>(pr);
            *reinterpret_cast<uint4*>(&sR[c][kc + 8]) = *reinterpret_cast<const uint4*>(pr + 8);
        }
        __syncthreads();
        int kchunk = (lane >> 4) * 8;
        bf16x8 af = *reinterpret_cast<const bf16x8*>(&sA[w * 16 + (lane & 15)][kchunk]);
#pragma unroll
        for (int f = 0; f < 8; ++f){
            bf16x8 bfl = *reinterpret_cast<const bf16x8*>(&sL[f * 16 + (lane & 15)][kchunk]);
            accL[f] = __builtin_amdgcn_mfma_f32_16x16x32_bf16(af, bfl, accL[f], 0, 0, 0);
            bf16x8 bfr = *reinterpret_cast<const bf16x8*>(&sR[f * 16 + (lane & 15)][kchunk]);
            accR[f] = __builtin_amdgcn_mfma_f32_16x16x32_bf16(af, bfr, accR[f], 0, 0, 0);
        }
        __syncthreads();
    }
    int colL = lane & 15;
    int rbase = (lane >> 4) * 4;
#pragma unroll
    for (int f = 0; f < 8; ++f){
        int col = c0 + f * 16 + colL;
        float bvl = bl[col];
        float bvr = br[col];
#pragma unroll
        for (int r = 0; r < 4; ++r){
            int gr = r0 + w * 16 + rbase + r;
            if (gr < N_NODES){
                xlh[(size_t)gr * HC + col] = __float2bfloat16(accL[f][r] + bvl);
                xrh[(size_t)gr * HC + col] = f2b(accR[f][r] + bvr);
            }
        }
    }
}

// ---------------- fused per-node: logits + softmax + aggregate + epilogue ----------------
// R8 EXACT (best known: 93.6us/dispatch, VGPR=48, occ 46%): f16 We via fdot2,
// scalar-uniform metadata (SMEM es + SALU control), simple batch-4 loop.
// CLOSED LEVERS (do not retry): batch-8 (R9: +5us, VGPR 60), depth-2 pipeline
// (R10: +6us, VGPR 52), occupancy attrs (R2/R7). At VGPR=48/18 waves-CU the
// inter-wave TLP already hides gather latency; any extra live state regresses.
// MODE 0: layer 1 -> relu + layernorm -> h1 (bf16);  MODE 1: layer 2 -> f32 output
template<int MODE>
__global__ __launch_bounds__(256)
__attribute__((amdgpu_waves_per_eu(4, 8)))
void k_fused(const bf16* __restrict__ xlh, const unsigned short* __restrict__ xrh,
             const _Float16* __restrict__ eah,
             const int2* __restrict__ es, const int* __restrict__ ptr,
             const int* __restrict__ ord,
             const _Float16* __restrict__ wehT, const float* __restrict__ att,
             const float* __restrict__ bias, const float* __restrict__ lng,
             const float* __restrict__ lnb,
             unsigned short* __restrict__ h1b, float* __restrict__ outF){
    const int wv = threadIdx.x >> 6;
    const int lane = threadIdx.x & 63;
    const int c0 = lane * 4;
    const int k = lane & 7;

    // wave-invariant: We column slice in f16 pairs (32 VGPRs) + att slice
    h2f wh[4][8];
#pragma unroll
    for (int c = 0; c < 4; ++c){
        uint4 wa = *reinterpret_cast<const uint4*>(wehT + (size_t)(c0 + c) * ED_F);
        uint4 wb = *reinterpret_cast<const uint4*>(wehT + (size_t)(c0 + c) * ED_F + 8);
        wh[c][0] = u2h(wa.x); wh[c][1] = u2h(wa.y); wh[c][2] = u2h(wa.z); wh[c][3] = u2h(wa.w);
        wh[c][4] = u2h(wb.x); wh[c][5] = u2h(wb.y); wh[c][6] = u2h(wb.z); wh[c][7] = u2h(wb.w);
    }
    float4 at4 = *reinterpret_cast<const float4*>(att + c0);
    // fold ln2-conversion into att: exp(z.att) == exp2(z.(att*log2e))
    at4.x *= 1.44269504f; at4.y *= 1.44269504f; at4.z *= 1.44269504f; at4.w *= 1.44269504f;

#define EDGE_MLP(PK, AR, U)                                               \
        {                                                                 \
            uint4 ua = *reinterpret_cast<const uint4*>(AR);               \
            uint4 ub = *reinterpret_cast<const uint4*>(AR + 8);           \
            h2f eh_[8] = {u2h(ua.x), u2h(ua.y), u2h(ua.z), u2h(ua.w),     \
                          u2h(ub.x), u2h(ub.y), u2h(ub.z), u2h(ub.w)};    \
            float z0 = bfu(U.x) + xr0, z1 = bfu(U.y) + xr1;               \
            float z2 = bfu(U.z) + xr2, z3 = bfu(U.w) + xr3;               \
            _Pragma("unroll")                                             \
            for (int j2 = 0; j2 < 8; ++j2){                               \
                z0 = __builtin_amdgcn_fdot2(eh_[j2], wh[0][j2], z0, false);\
                z1 = __builtin_amdgcn_fdot2(eh_[j2], wh[1][j2], z1, false);\
                z2 = __builtin_amdgcn_fdot2(eh_[j2], wh[2][j2], z2, false);\
                z3 = __builtin_amdgcn_fdot2(eh_[j2], wh[3][j2], z3, false);\
            }                                                             \
            z0 = fmaxf(z0, NEG_SLOPE * z0);                               \
            z1 = fmaxf(z1, NEG_SLOPE * z1);                               \
            z2 = fmaxf(z2, NEG_SLOPE * z2);                               \
            z3 = fmaxf(z3, NEG_SLOPE * z3);                               \
            PK = z0 * at4.x + z1 * at4.y + z2 * at4.z + z3 * at4.w;       \
        }

    const int nw = KF_NB * 4;
    for (int idx = blockIdx.x * 4 + wv; idx < N_NODES; idx += nw){
        // scalar-uniform node metadata: SMEM es loads + SALU loop control
        int n = __builtin_amdgcn_readfirstlane(ord[idx]);
        int b = __builtin_amdgcn_readfirstlane(ptr[n]);
        int tend = __builtin_amdgcn_readfirstlane(ptr[n + 1]);

        ushort4 xu = *reinterpret_cast<const ushort4*>(xrh + (size_t)n * HC + c0);
        float xr0 = bfu(xu.x), xr1 = bfu(xu.y), xr2 = bfu(xu.z), xr3 = bfu(xu.w);

        float ssum = 0.f;
        v2f accv[2] = {v2f{0.f, 0.f}, v2f{0.f, 0.f}};

        int i = b;
        // ---- full batches of 4: no clamping, no predication ----
        for (; i + 4 <= tend; i += 4){
            int2 q0 = es[i], q1 = es[i + 1], q2 = es[i + 2], q3 = es[i + 3];
            int e0 = __builtin_amdgcn_readfirstlane(q0.x);
            int s0 = __builtin_amdgcn_readfirstlane(q0.y);
            int e1 = __builtin_amdgcn_readfirstlane(q1.x);
            int s1 = __builtin_amdgcn_readfirstlane(q1.y);
            int e2 = __builtin_amdgcn_readfirstlane(q2.x);
            int s2 = __builtin_amdgcn_readfirstlane(q2.y);
            int e3 = __builtin_amdgcn_readfirstlane(q3.x);
            int s3 = __builtin_amdgcn_readfirstlane(q3.y);
            const _Float16* ar0 = eah + (size_t)e0 * ED_F;
            const _Float16* ar1 = eah + (size_t)e1 * ED_F;
            const _Float16* ar2 = eah + (size_t)e2 * ED_F;
            const _Float16* ar3 = eah + (size_t)e3 * ED_F;

            ushort4 u0 = *reinterpret_cast<const ushort4*>(xlh + (size_t)s0 * HC + c0);
            ushort4 u1 = *reinterpret_cast<const ushort4*>(xlh + (size_t)s1 * HC + c0);
            ushort4 u2 = *reinterpret_cast<const ushort4*>(xlh + (size_t)s2 * HC + c0);
            ushort4 u3 = *reinterpret_cast<const ushort4*>(xlh + (size_t)s3 * HC + c0);

            float p0, p1, p2, p3;
            EDGE_MLP(p0, ar0, u0)
            EDGE_MLP(p1, ar1, u1)
            EDGE_MLP(p2, ar2, u2)
            EDGE_MLP(p3, ar3, u3)

            p0 += __shfl_xor(p0, 1, 64); p1 += __shfl_xor(p1, 1, 64);
            p2 += __shfl_xor(p2, 1, 64); p3 += __shfl_xor(p3, 1, 64);
            p0 += __shfl_xor(p0, 2, 64); p1 += __shfl_xor(p1, 2, 64);
            p2 += __shfl_xor(p2, 2, 64); p3 += __shfl_xor(p3, 2, 64);
            p0 += __shfl_xor(p0, 4, 64); p1 += __shfl_xor(p1, 4, 64);
            p2 += __shfl_xor(p2, 4, 64); p3 += __shfl_xor(p3, 4, 64);

            float w0 = __builtin_amdgcn_exp2f(p0);
            float w1 = __builtin_amdgcn_exp2f(p1);
            float w2 = __builtin_amdgcn_exp2f(p2);
            float w3 = __builtin_amdgcn_exp2f(p3);
            ssum += w0 + w1 + w2 + w3;
            v2f w0v = {w0, w0}, w1v = {w1, w1}, w2v = {w2, w2}, w3v = {w3, w3};
            accv[0] += w0v * v2f{bfu(u0.x), bfu(u0.y)} + w1v * v2f{bfu(u1.x), bfu(u1.y)}
                     + w2v * v2f{bfu(u2.x), bfu(u2.y)} + w3v * v2f{bfu(u3.x), bfu(u3.y)};
            accv[1] += w0v * v2f{bfu(u0.z), bfu(u0.w)} + w1v * v2f{bfu(u1.z), bfu(u1.w)}
                     + w2v * v2f{bfu(u2.z), bfu(u2.w)} + w3v * v2f{bfu(u3.z), bfu(u3.w)};
        }
        // ---- exact remainder (0..3 edges) ----
        for (; i < tend; ++i){
            int2 q0 = es[i];
            int e0 = __builtin_amdgcn_readfirstlane(q0.x);
            int s0 = __builtin_amdgcn_readfirstlane(q0.y);
            const _Float16* ar0 = eah + (size_t)e0 * ED_F;
            ushort4 u0 = *reinterpret_cast<const ushort4*>(xlh + (size_t)s0 * HC + c0);
            float p0;
            EDGE_MLP(p0, ar0, u0)
            p0 += __shfl_xor(p0, 1, 64);
            p0 += __shfl_xor(p0, 2, 64);
            p0 += __shfl_xor(p0, 4, 64);
            float w0 = __builtin_amdgcn_exp2f(p0);
            ssum += w0;
            v2f w0v = {w0, w0};
            accv[0] += w0v * v2f{bfu(u0.x), bfu(u0.y)};
            accv[1] += w0v * v2f{bfu(u0.z), bfu(u0.w)};
        }

        float inv = __builtin_amdgcn_rcpf(ssum + 1e-16f);
        float acc[4] = {accv[0].x * inv, accv[0].y * inv, accv[1].x * inv, accv[1].y * inv};
#pragma unroll
        for (int q = 0; q < 4; ++q){
            acc[q] += __shfl_xor(acc[q], 8, 64);
            acc[q] += __shfl_xor(acc[q], 16, 64);
            acc[q] += __shfl_xor(acc[q], 32, 64);
        }
        float val[4];
#pragma unroll
        for (int q = 0; q < 4; ++q) val[q] = acc[q] * 0.125f + bias[k * 4 + q];

        if (MODE == 0){
            float r[4], s1 = 0.f, s2 = 0.f;
#pragma unroll
            for (int q = 0; q < 4; ++q){ r[q] = fmaxf(val[q], 0.f); s1 += r[q]; s2 += r[q] * r[q]; }
#pragma unroll
            for (int msk = 1; msk <= 4; msk <<= 1){
                s1 += __shfl_xor(s1, msk, 64);
                s2 += __shfl_xor(s2, msk, 64);
            }
            float mu = s1 * (1.f / 32.f);
            float var = s2 * (1.f / 32.f) - mu * mu;
            float rinv = rsqrtf(var + LN_EPS);
            if (lane < 8){
                unsigned short o[4];
#pragma unroll
                for (int q = 0; q < 4; ++q)
                    o[q] = f2b((r[q] - mu) * rinv * lng[k * 4 + q] + lnb[k * 4 + q]);
                *reinterpret_cast<ushort4*>(h1b + (size_t)n * C_CH + k * 4) =
                    *reinterpret_cast<ushort4*>(o);
            }
        } else {
            if (lane < 8){
                *reinterpret_cast<float4*>(outF + (size_t)n * C_CH + k * 4) =
                    make_float4(val[0], val[1], val[2], val[3]);
            }
        }
    }
#undef EDGE_MLP
}

// ---------------- launch ----------------

extern "C" void kernel_launch(void* const* d_in, const int* in_sizes, int n_in,
                              void* d_out, int out_size, void* d_ws, size_t ws_size,
                              hipStream_t stream){
    const float* x    = (const float*)d_in[0];
    const int*   ei   = (const int*)d_in[1];
    const float* ea   = (const float*)d_in[2];
    const float* Wl1  = (const float*)d_in[3];
    const float* bl1  = (const float*)d_in[4];
    const float* Wr1  = (const float*)d_in[5];
    const float* br1  = (const float*)d_in[6];
    const float* We1  = (const float*)d_in[7];
    const float* att1 = (const float*)d_in[8];
    const float* bias1= (const float*)d_in[9];
    const float* Wl2  = (const float*)d_in[10];
    const float* bl2  = (const float*)d_in[11];
    const float* Wr2  = (const float*)d_in[12];
    const float* br2  = (const float*)d_in[13];
    const float* We2  = (const float*)d_in[14];
    const float* att2 = (const float*)d_in[15];
    const float* bias2= (const float*)d_in[16];
    const float* lng  = (const float*)d_in[17];
    const float* lnb  = (const float*)d_in[18];
    const int* srcA = ei;
    const int* dstA = ei + N_EDGES;

    // workspace layout (~95 MB)
    char* w = (char*)d_ws;
    bf16*  xlh = (bf16*)w;                    w += (size_t)N_NODES * HC * 2;
    unsigned short* xrh = (unsigned short*)w; w += (size_t)N_NODES * HC * 2;
    unsigned short* xb  = (unsigned short*)w; w += (size_t)N_NODES * IN_F * 2;
    unsigned short* h1b = (unsigned short*)w; w += (size_t)N_NODES * C_CH * 2;
    // eah and lah MUST stay contiguous: k_fused indexes eah + e*ED_F for
    // e in [0, EP) -- self-loop rows (e >= N_EDGES) land in lah.
    _Float16* eah = (_Float16*)w;             w += (size_t)N_EDGES * ED_F * 2;
    _Float16* lah = (_Float16*)w;             w += (size_t)N_NODES * ED_F * 2;
    _Float16* weh1T = (_Float16*)w;           w += (size_t)HC * ED_F * 2;
    _Float16* weh2T = (_Float16*)w;           w += (size_t)HC * ED_F * 2;
    unsigned short* Wt1l = (unsigned short*)w; w += (size_t)HC * IN_F * 2;
    unsigned short* Wt1r = (unsigned short*)w; w += (size_t)HC * IN_F * 2;
    unsigned short* Wt2l = (unsigned short*)w; w += (size_t)HC * C_CH * 2;
    unsigned short* Wt2r = (unsigned short*)w; w += (size_t)HC * C_CH * 2;
    // contiguous zero region: deg | cur | hist | hcur  (one memset)
    int* deg   = (int*)w;   w += (size_t)N_NODES * 4;
    int* cur   = (int*)w;   w += (size_t)N_NODES * 4;
    int* hist  = (int*)w;   w += (size_t)NDBINS * 4;
    int* hcur  = (int*)w;   w += (size_t)NDBINS * 4;
    int* ptr   = (int*)w;   w += (size_t)(N_NODES + 1) * 4;
    int2* es   = (int2*)w;  w += (size_t)EP * 8;
    int* bsum  = (int*)w;   w += (size_t)(NB_SCAN + 1) * 4;
    int* boff  = (int*)w;   w += (size_t)(NB_SCAN + 1) * 4;
    int* hoff  = (int*)w;   w += (size_t)NDBINS * 4;
    int* ord   = (int*)w;   w += (size_t)N_NODES * 4;

    hipMemsetAsync(deg, 0, (size_t)(2 * N_NODES + 2 * NDBINS) * 4, stream);

    // combined casts / weight prep / degree count (one launch)
    k_prep<<<PREP_W_END + 2 + DEG_NB, 256, 0, stream>>>(
        x, xb, ea, eah, Wl1, Wt1l, Wr1, Wt1r, Wl2, Wt2l, Wr2, Wt2r,
        We1, weh1T, We2, weh2T, dstA, deg);

    k_scanA<<<NB_SCAN, 256, 0, stream>>>(deg, ptr, bsum, hist);
    k_scanBH<<<1, 256, 0, stream>>>(bsum, boff, hist, hoff);
    k_scanC<<<(N_NODES + 256) / 256, 256, 0, stream>>>(ptr, boff);
    k_scatter<<<(EP + 255) / 256, 256, 0, stream>>>(srcA, dstA, ptr, cur, es);
    k_loopattr<<<(N_NODES * ED_F + 255) / 256, 256, 0, stream>>>(ptr, es, ea, deg, lah);
    k_place<<<(N_NODES + 255) / 256, 256, 0, stream>>>(ptr, hoff, hcur, ord);

    // layer 1
    dim3 gg((N_NODES + 63) / 64, 2);
    k_gemmM<IN_F><<<gg, 256, 0, stream>>>(xb, Wt1l, bl1, Wt1r, br1, xlh, xrh);
    k_fused<0><<<KF_NB, 256, 0, stream>>>(xlh, xrh, eah, es, ptr, ord, weh1T, att1,
                                          bias1, lng, lnb, h1b, nullptr);
    // layer 2
    k_gemmM<C_CH><<<gg, 256, 0, stream>>>(h1b, Wt2l, bl2, Wt2r, br2, xlh, xrh);
    k_fused<1><<<KF_NB, 256, 0, stream>>>(xlh, xrh, eah, es, ptr, ord, weh2T, att2,
                                          bias2, nullptr, nullptr, nullptr, (float*)d_out);
}

// Round 12
// 324.083 us; speedup vs baseline: 1.0246x; 1.0246x over previous
//
#include <hip/hip_runtime.h>
#include <hip/hip_bf16.h>

// Problem constants (from reference)
#define N_NODES 50000
#define N_EDGES 400000
#define EP (N_EDGES + N_NODES)   // edges incl. self loops = 450000
#define IN_F 128
#define H_HEADS 8
#define C_CH 32
#define HC 256                   // H*C
#define ED_F 16
#define NEG_SLOPE 0.2f
#define LN_EPS 1e-5f
#define NB_SCAN ((N_NODES + 2047) / 2048)   // 25 blocks in phase-A scan
#define KF_NB 4096

typedef __hip_bfloat16 bf16;
typedef float v2f __attribute__((ext_vector_type(2)));
typedef short bf16x8 __attribute__((ext_vector_type(8)));
typedef float f32x4 __attribute__((ext_vector_type(4)));
typedef _Float16 h2f __attribute__((ext_vector_type(2)));

__device__ __forceinline__ float bfu(unsigned short v){
    return __uint_as_float((unsigned int)v << 16);
}
__device__ __forceinline__ unsigned short f2b(float v){
    bf16 t = __float2bfloat16(v);
    return *reinterpret_cast<unsigned short*>(&t);
}
__device__ __forceinline__ h2f u2h(unsigned int u){
    union { unsigned int u; h2f h; } x; x.u = u; return x.h;
}

// ---------------- combined input casts / weight prep / degree count (one kernel) ----------------
#define CASTX_NB 3125
#define CASTE_NB 3125
#define W1_NB 128
#define W2_NB 32
#define DEG_NB ((N_EDGES + 255) / 256)
#define PREP_W_END (CASTX_NB + CASTE_NB + 2 * W1_NB + 2 * W2_NB)   // 6570

__device__ __forceinline__ void prepW_body(const float* __restrict__ W,
                                           unsigned short* __restrict__ Wt,
                                           int K, int idx){
    if (idx >= 256 * K) return;
    int c = idx & 255, k = idx >> 8;
    Wt[(size_t)c * K + k] = f2b(W[idx]);
}

__global__ void k_prep(const float* __restrict__ x, unsigned short* __restrict__ xb,
                       const float* __restrict__ ea, _Float16* __restrict__ eah,
                       const float* __restrict__ Wl1, unsigned short* __restrict__ Wt1l,
                       const float* __restrict__ Wr1, unsigned short* __restrict__ Wt1r,
                       const float* __restrict__ Wl2, unsigned short* __restrict__ Wt2l,
                       const float* __restrict__ Wr2, unsigned short* __restrict__ Wt2r,
                       const float* __restrict__ We1, _Float16* __restrict__ weh1T,
                       const float* __restrict__ We2, _Float16* __restrict__ weh2T,
                       const int* __restrict__ dstA, int* __restrict__ deg){
    int b = blockIdx.x, t = threadIdx.x;
    if (b < CASTX_NB){
        int i = b * 256 + t;
        if (i >= N_NODES * IN_F / 8) return;
        const float4* p = reinterpret_cast<const float4*>(x + (size_t)i * 8);
        float4 v0 = p[0], v1 = p[1];
        unsigned short o[8] = {f2b(v0.x), f2b(v0.y), f2b(v0.z), f2b(v0.w),
                               f2b(v1.x), f2b(v1.y), f2b(v1.z), f2b(v1.w)};
        *reinterpret_cast<uint4*>(xb + (size_t)i * 8) = *reinterpret_cast<uint4*>(o);
    } else if (b < CASTX_NB + CASTE_NB){
        int i = (b - CASTX_NB) * 256 + t;     // < 800000 exactly
        const float4* p = reinterpret_cast<const float4*>(ea + (size_t)i * 8);
        float4 v0 = p[0], v1 = p[1];
        _Float16 o[8] = {(_Float16)v0.x, (_Float16)v0.y, (_Float16)v0.z, (_Float16)v0.w,
                         (_Float16)v1.x, (_Float16)v1.y, (_Float16)v1.z, (_Float16)v1.w};
        *reinterpret_cast<uint4*>(eah + (size_t)i * 8) = *reinterpret_cast<uint4*>(o);
    } else if (b < CASTX_NB + CASTE_NB + W1_NB){
        prepW_body(Wl1, Wt1l, IN_F, (b - CASTX_NB - CASTE_NB) * 256 + t);
    } else if (b < CASTX_NB + CASTE_NB + 2 * W1_NB){
        prepW_body(Wr1, Wt1r, IN_F, (b - CASTX_NB - CASTE_NB - W1_NB) * 256 + t);
    } else if (b < CASTX_NB + CASTE_NB + 2 * W1_NB + W2_NB){
        prepW_body(Wl2, Wt2l, C_CH, (b - CASTX_NB - CASTE_NB - 2 * W1_NB) * 256 + t);
    } else if (b < PREP_W_END){
        prepW_body(Wr2, Wt2r, C_CH, (b - CASTX_NB - CASTE_NB - 2 * W1_NB - W2_NB) * 256 + t);
    } else if (b == PREP_W_END){
        // We1^T: weh1T[c][j] = We1[j][c], f16, 16 contiguous per channel
#pragma unroll
        for (int j = 0; j < ED_F; ++j)
            weh1T[t * ED_F + j] = (_Float16)We1[j * HC + t];
    } else if (b == PREP_W_END + 1){
#pragma unroll
        for (int j = 0; j < ED_F; ++j)
            weh2T[t * ED_F + j] = (_Float16)We2[j * HC + t];
    } else {
        // merged k_deg
        int e = (b - PREP_W_END - 2) * 256 + t;
        if (e < N_EDGES) atomicAdd(&deg[dstA[e]], 1);
    }
}

// ---------------- CSR build ----------------
// NOTE: degree-balanced ord[] pipeline REMOVED (R12): in-degree ~ Poisson(8)
// (uniform random graph, max ~30) so per-wave work is naturally balanced, and
// natural node order gives contiguous ptr/es/xrh/h1b access across waves.

__global__ void k_scanA(const int* __restrict__ deg, int* __restrict__ ptr,
                        int* __restrict__ bsum){
    __shared__ int wsum[4];
    int blk = blockIdx.x;
    int base0 = blk * 2048;
    int t = threadIdx.x, lane = t & 63, wv = t >> 6;
    int carry = 0;
    for (int c = 0; c < 8; ++c){
        int i = base0 + c * 256 + t;
        int v = (i < N_NODES) ? (deg[i] + 1) : 0;
        int x = v;
#pragma unroll
        for (int off = 1; off < 64; off <<= 1){
            int y = __shfl_up(x, off, 64);
            if (lane >= off) x += y;
        }
        if (lane == 63) wsum[wv] = x;
        __syncthreads();
        int pre = carry;
        for (int j = 0; j < wv; ++j) pre += wsum[j];
        if (i < N_NODES) ptr[i] = pre + x - v;
        int tot = wsum[0] + wsum[1] + wsum[2] + wsum[3];
        __syncthreads();
        carry += tot;
    }
    if (t == 0) bsum[blk] = carry;
}

__global__ void k_scanB(const int* __restrict__ bsum, int* __restrict__ boff){
    int t = threadIdx.x;   // 64 threads
    int v = (t < NB_SCAN) ? bsum[t] : 0;
    int x = v;
#pragma unroll
    for (int off = 1; off < 64; off <<= 1){
        int y = __shfl_up(x, off, 64);
        if (t >= off) x += y;
    }
    if (t < NB_SCAN) boff[t] = x - v;
    if (t == 63) boff[NB_SCAN] = x;
}

__global__ void k_scanC(int* __restrict__ ptr, const int* __restrict__ boff){
    int i = blockIdx.x * 256 + threadIdx.x;
    if (i < N_NODES) ptr[i] += boff[i >> 11];
    else if (i == N_NODES) ptr[i] = boff[NB_SCAN];
}

// scatter edges into CSR slots and emit (edge, src) pairs directly.
__global__ void k_scatter(const int* __restrict__ srcA, const int* __restrict__ dstA,
                          const int* __restrict__ ptr, int* __restrict__ cur,
                          int2* __restrict__ es){
    int e = blockIdx.x * 256 + threadIdx.x;
    if (e >= EP) return;
    int n, s;
    if (e < N_EDGES){ n = dstA[e]; s = srcA[e]; }
    else            { n = e - N_EDGES; s = n; }
    int p = ptr[n] + atomicAdd(&cur[n], 1);
    es[p] = make_int2(e, s);
}

__global__ void k_loopattr(const int* __restrict__ ptr, const int2* __restrict__ es,
                           const float* __restrict__ ea, const int* __restrict__ deg,
                           _Float16* __restrict__ lah){
    int idx = blockIdx.x * 256 + threadIdx.x;
    if (idx >= N_NODES * ED_F) return;
    int n = idx >> 4, j = idx & 15;
    float s = 0.f;
    int b = ptr[n], t = ptr[n + 1];
    for (int i = b; i < t; ++i){
        int e = es[i].x;
        if (e < N_EDGES) s += ea[(size_t)e * ED_F + j];
    }
    lah[idx] = (_Float16)(s / (float)max(deg[n], 1));
}

// ---------------- MFMA pair GEMM: xl(bf16) = A@Wl + bl, xr(bf16) = A@Wr + br ----------------
// R8 structure (reverted from R11's merged-pair attempt: 2x accumulators cut
// block residency and regressed ~11us — this gemm is occupancy-bound, not
// A-fetch-bound). A bf16 [N][K]; Wt* bf16 [256][K]. 64 rows x 128 cols, 4 waves.
template<int K>
__global__ __launch_bounds__(256)
void k_gemmM(const unsigned short* __restrict__ A,
             const unsigned short* __restrict__ Wtl, const float* __restrict__ bl,
             const unsigned short* __restrict__ Wtr, const float* __restrict__ br,
             bf16* __restrict__ xlh, unsigned short* __restrict__ xrh){
    const int cb = blockIdx.y;            // 0..3: {Wl c0=0, Wl c0=128, Wr c0=0, Wr c0=128}
    const unsigned short* Wt = (cb < 2) ? Wtl : Wtr;
    const float* bs = (cb < 2) ? bl : br;
    const int c0 = (cb & 1) * 128;
    const int r0 = blockIdx.x * 64;

    __shared__ unsigned short sA[64][40];
    __shared__ unsigned short sW[128][40];

    const int tid = threadIdx.x;
    const int lane = tid & 63;
    const int w = tid >> 6;

    f32x4 acc[8] = {};

    for (int kt = 0; kt < K; kt += 32){
        {   // stage A: 64 rows x 32 k
            int row = tid >> 2, kc = (tid & 3) * 8;
            int gr = r0 + row;
            uint4 v = make_uint4(0, 0, 0, 0);
            if (gr < N_NODES)
                v = *reinterpret_cast<const uint4*>(&A[(size_t)gr * K + kt + kc]);
            *reinterpret_cast<uint4*>(&sA[row][kc]) = v;
        }
        {   // stage W: 128 cols x 32 k
            int c = tid >> 1, kc = (tid & 1) * 16;
            const unsigned short* src = &Wt[(size_t)(c0 + c) * K + kt + kc];
            *reinterpret_cast<uint4*>(&sW[c][kc])     = *reinterpret_cast<const uint4*>(src);
            *reinterpret_cast<uint4*>(&sW[c][kc + 8]) = *reinterpret_cast<const uint4*>(src + 8);
        }
        __syncthreads();
        int kchunk = (lane >> 4) * 8;
        bf16x8 af = *reinterpret_cast<const bf16x8*>(&sA[w * 16 + (lane & 15)][kchunk]);
#pragma unroll
        for (int f = 0; f < 8; ++f){
            bf16x8 bfr = *reinterpret_cast<const bf16x8*>(&sW[f * 16 + (lane & 15)][kchunk]);
            acc[f] = __builtin_amdgcn_mfma_f32_16x16x32_bf16(af, bfr, acc[f], 0, 0, 0);
        }
        __syncthreads();
    }
    int colL = lane & 15;
    int rbase = (lane >> 4) * 4;
#pragma unroll
    for (int f = 0; f < 8; ++f){
        int col = c0 + f * 16 + colL;
        float bv = bs[col];
#pragma unroll
        for (int r = 0; r < 4; ++r){
            int gr = r0 + w * 16 + rbase + r;
            if (gr < N_NODES){
                float ov = acc[f][r] + bv;
                if (cb < 2) xlh[(size_t)gr * HC + col] = __float2bfloat16(ov);
                else        xrh[(size_t)gr * HC + col] = f2b(ov);
            }
        }
    }
}

// ---------------- fused per-node: logits + softmax + aggregate + epilogue ----------------
// R8 EXACT loop (best known: 93.6us/dispatch, VGPR=48, occ 46%) with ord[]
// indirection removed: n = idx directly (natural order -> contiguous ptr/es/
// xrh/h1b access across adjacent waves; degree is Poisson(8), no balance need).
// CLOSED LEVERS (do not retry): batch-8 (R9), depth-2 pipeline (R10),
// occupancy attrs (R2/R7). At VGPR=48 inter-wave TLP hides gather latency;
// any extra live state regresses.
// MODE 0: layer 1 -> relu + layernorm -> h1 (bf16);  MODE 1: layer 2 -> f32 output
template<int MODE>
__global__ __launch_bounds__(256)
__attribute__((amdgpu_waves_per_eu(4, 8)))
void k_fused(const bf16* __restrict__ xlh, const unsigned short* __restrict__ xrh,
             const _Float16* __restrict__ eah,
             const int2* __restrict__ es, const int* __restrict__ ptr,
             const _Float16* __restrict__ wehT, const float* __restrict__ att,
             const float* __restrict__ bias, const float* __restrict__ lng,
             const float* __restrict__ lnb,
             unsigned short* __restrict__ h1b, float* __restrict__ outF){
    const int wv = threadIdx.x >> 6;
    const int lane = threadIdx.x & 63;
    const int c0 = lane * 4;
    const int k = lane & 7;

    // wave-invariant: We column slice in f16 pairs (32 VGPRs) + att slice
    h2f wh[4][8];
#pragma unroll
    for (int c = 0; c < 4; ++c){
        uint4 wa = *reinterpret_cast<const uint4*>(wehT + (size_t)(c0 + c) * ED_F);
        uint4 wb = *reinterpret_cast<const uint4*>(wehT + (size_t)(c0 + c) * ED_F + 8);
        wh[c][0] = u2h(wa.x); wh[c][1] = u2h(wa.y); wh[c][2] = u2h(wa.z); wh[c][3] = u2h(wa.w);
        wh[c][4] = u2h(wb.x); wh[c][5] = u2h(wb.y); wh[c][6] = u2h(wb.z); wh[c][7] = u2h(wb.w);
    }
    float4 at4 = *reinterpret_cast<const float4*>(att + c0);
    // fold ln2-conversion into att: exp(z.att) == exp2(z.(att*log2e))
    at4.x *= 1.44269504f; at4.y *= 1.44269504f; at4.z *= 1.44269504f; at4.w *= 1.44269504f;

#define EDGE_MLP(PK, AR, U)                                               \
        {                                                                 \
            uint4 ua = *reinterpret_cast<const uint4*>(AR);               \
            uint4 ub = *reinterpret_cast<const uint4*>(AR + 8);           \
            h2f eh_[8] = {u2h(ua.x), u2h(ua.y), u2h(ua.z), u2h(ua.w),     \
                          u2h(ub.x), u2h(ub.y), u2h(ub.z), u2h(ub.w)};    \
            float z0 = bfu(U.x) + xr0, z1 = bfu(U.y) + xr1;               \
            float z2 = bfu(U.z) + xr2, z3 = bfu(U.w) + xr3;               \
            _Pragma("unroll")                                             \
            for (int j2 = 0; j2 < 8; ++j2){                               \
                z0 = __builtin_amdgcn_fdot2(eh_[j2], wh[0][j2], z0, false);\
                z1 = __builtin_amdgcn_fdot2(eh_[j2], wh[1][j2], z1, false);\
                z2 = __builtin_amdgcn_fdot2(eh_[j2], wh[2][j2], z2, false);\
                z3 = __builtin_amdgcn_fdot2(eh_[j2], wh[3][j2], z3, false);\
            }                                                             \
            z0 = fmaxf(z0, NEG_SLOPE * z0);                               \
            z1 = fmaxf(z1, NEG_SLOPE * z1);                               \
            z2 = fmaxf(z2, NEG_SLOPE * z2);                               \
            z3 = fmaxf(z3, NEG_SLOPE * z3);                               \
            PK = z0 * at4.x + z1 * at4.y + z2 * at4.z + z3 * at4.w;       \
        }

    const int nw = KF_NB * 4;
    for (int n = blockIdx.x * 4 + wv; n < N_NODES; n += nw){
        // n is wave-uniform scalar; ptr loads go through SMEM path
        int b = __builtin_amdgcn_readfirstlane(ptr[n]);
        int tend = __builtin_amdgcn_readfirstlane(ptr[n + 1]);

        ushort4 xu = *reinterpret_cast<const ushort4*>(xrh + (size_t)n * HC + c0);
        float xr0 = bfu(xu.x), xr1 = bfu(xu.y), xr2 = bfu(xu.z), xr3 = bfu(xu.w);

        float ssum = 0.f;
        v2f accv[2] = {v2f{0.f, 0.f}, v2f{0.f, 0.f}};

        int i = b;
        // ---- full batches of 4: no clamping, no predication ----
        for (; i + 4 <= tend; i += 4){
            int2 q0 = es[i], q1 = es[i + 1], q2 = es[i + 2], q3 = es[i + 3];
            int e0 = __builtin_amdgcn_readfirstlane(q0.x);
            int s0 = __builtin_amdgcn_readfirstlane(q0.y);
            int e1 = __builtin_amdgcn_readfirstlane(q1.x);
            int s1 = __builtin_amdgcn_readfirstlane(q1.y);
            int e2 = __builtin_amdgcn_readfirstlane(q2.x);
            int s2 = __builtin_amdgcn_readfirstlane(q2.y);
            int e3 = __builtin_amdgcn_readfirstlane(q3.x);
            int s3 = __builtin_amdgcn_readfirstlane(q3.y);
            const _Float16* ar0 = eah + (size_t)e0 * ED_F;
            const _Float16* ar1 = eah + (size_t)e1 * ED_F;
            const _Float16* ar2 = eah + (size_t)e2 * ED_F;
            const _Float16* ar3 = eah + (size_t)e3 * ED_F;

            ushort4 u0 = *reinterpret_cast<const ushort4*>(xlh + (size_t)s0 * HC + c0);
            ushort4 u1 = *reinterpret_cast<const ushort4*>(xlh + (size_t)s1 * HC + c0);
            ushort4 u2 = *reinterpret_cast<const ushort4*>(xlh + (size_t)s2 * HC + c0);
            ushort4 u3 = *reinterpret_cast<const ushort4*>(xlh + (size_t)s3 * HC + c0);

            float p0, p1, p2, p3;
            EDGE_MLP(p0, ar0, u0)
            EDGE_MLP(p1, ar1, u1)
            EDGE_MLP(p2, ar2, u2)
            EDGE_MLP(p3, ar3, u3)

            p0 += __shfl_xor(p0, 1, 64); p1 += __shfl_xor(p1, 1, 64);
            p2 += __shfl_xor(p2, 1, 64); p3 += __shfl_xor(p3, 1, 64);
            p0 += __shfl_xor(p0, 2, 64); p1 += __shfl_xor(p1, 2, 64);
            p2 += __shfl_xor(p2, 2, 64); p3 += __shfl_xor(p3, 2, 64);
            p0 += __shfl_xor(p0, 4, 64); p1 += __shfl_xor(p1, 4, 64);
            p2 += __shfl_xor(p2, 4, 64); p3 += __shfl_xor(p3, 4, 64);

            float w0 = __builtin_amdgcn_exp2f(p0);
            float w1 = __builtin_amdgcn_exp2f(p1);
            float w2 = __builtin_amdgcn_exp2f(p2);
            float w3 = __builtin_amdgcn_exp2f(p3);
            ssum += w0 + w1 + w2 + w3;
            v2f w0v = {w0, w0}, w1v = {w1, w1}, w2v = {w2, w2}, w3v = {w3, w3};
            accv[0] += w0v * v2f{bfu(u0.x), bfu(u0.y)} + w1v * v2f{bfu(u1.x), bfu(u1.y)}
                     + w2v * v2f{bfu(u2.x), bfu(u2.y)} + w3v * v2f{bfu(u3.x), bfu(u3.y)};
            accv[1] += w0v * v2f{bfu(u0.z), bfu(u0.w)} + w1v * v2f{bfu(u1.z), bfu(u1.w)}
                     + w2v * v2f{bfu(u2.z), bfu(u2.w)} + w3v * v2f{bfu(u3.z), bfu(u3.w)};
        }
        // ---- exact remainder (0..3 edges) ----
        for (; i < tend; ++i){
            int2 q0 = es[i];
            int e0 = __builtin_amdgcn_readfirstlane(q0.x);
            int s0 = __builtin_amdgcn_readfirstlane(q0.y);
            const _Float16* ar0 = eah + (size_t)e0 * ED_F;
            ushort4 u0 = *reinterpret_cast<const ushort4*>(xlh + (size_t)s0 * HC + c0);
            float p0;
            EDGE_MLP(p0, ar0, u0)
            p0 += __shfl_xor(p0, 1, 64);
            p0 += __shfl_xor(p0, 2, 64);
            p0 += __shfl_xor(p0, 4, 64);
            float w0 = __builtin_amdgcn_exp2f(p0);
            ssum += w0;
            v2f w0v = {w0, w0};
            accv[0] += w0v * v2f{bfu(u0.x), bfu(u0.y)};
            accv[1] += w0v * v2f{bfu(u0.z), bfu(u0.w)};
        }

        float inv = __builtin_amdgcn_rcpf(ssum + 1e-16f);
        float acc[4] = {accv[0].x * inv, accv[0].y * inv, accv[1].x * inv, accv[1].y * inv};
#pragma unroll
        for (int q = 0; q < 4; ++q){
            acc[q] += __shfl_xor(acc[q], 8, 64);
            acc[q] += __shfl_xor(acc[q], 16, 64);
            acc[q] += __shfl_xor(acc[q], 32, 64);
        }
        float val[4];
#pragma unroll
        for (int q = 0; q < 4; ++q) val[q] = acc[q] * 0.125f + bias[k * 4 + q];

        if (MODE == 0){
            float r[4], s1 = 0.f, s2 = 0.f;
#pragma unroll
            for (int q = 0; q < 4; ++q){ r[q] = fmaxf(val[q], 0.f); s1 += r[q]; s2 += r[q] * r[q]; }
#pragma unroll
            for (int msk = 1; msk <= 4; msk <<= 1){
                s1 += __shfl_xor(s1, msk, 64);
                s2 += __shfl_xor(s2, msk, 64);
            }
            float mu = s1 * (1.f / 32.f);
            float var = s2 * (1.f / 32.f) - mu * mu;
            float rinv = rsqrtf(var + LN_EPS);
            if (lane < 8){
                unsigned short o[4];
#pragma unroll
                for (int q = 0; q < 4; ++q)
                    o[q] = f2b((r[q] - mu) * rinv * lng[k * 4 + q] + lnb[k * 4 + q]);
                *reinterpret_cast<ushort4*>(h1b + (size_t)n * C_CH + k * 4) =
                    *reinterpret_cast<ushort4*>(o);
            }
        } else {
            if (lane < 8){
                *reinterpret_cast<float4*>(outF + (size_t)n * C_CH + k * 4) =
                    make_float4(val[0], val[1], val[2], val[3]);
            }
        }
    }
#undef EDGE_MLP
}

// ---------------- launch ----------------

extern "C" void kernel_launch(void* const* d_in, const int* in_sizes, int n_in,
                              void* d_out, int out_size, void* d_ws, size_t ws_size,
                              hipStream_t stream){
    const float* x    = (const float*)d_in[0];
    const int*   ei   = (const int*)d_in[1];
    const float* ea   = (const float*)d_in[2];
    const float* Wl1  = (const float*)d_in[3];
    const float* bl1  = (const float*)d_in[4];
    const float* Wr1  = (const float*)d_in[5];
    const float* br1  = (const float*)d_in[6];
    const float* We1  = (const float*)d_in[7];
    const float* att1 = (const float*)d_in[8];
    const float* bias1= (const float*)d_in[9];
    const float* Wl2  = (const float*)d_in[10];
    const float* bl2  = (const float*)d_in[11];
    const float* Wr2  = (const float*)d_in[12];
    const float* br2  = (const float*)d_in[13];
    const float* We2  = (const float*)d_in[14];
    const float* att2 = (const float*)d_in[15];
    const float* bias2= (const float*)d_in[16];
    const float* lng  = (const float*)d_in[17];
    const float* lnb  = (const float*)d_in[18];
    const int* srcA = ei;
    const int* dstA = ei + N_EDGES;

    // workspace layout (~95 MB)
    char* w = (char*)d_ws;
    bf16*  xlh = (bf16*)w;                    w += (size_t)N_NODES * HC * 2;
    unsigned short* xrh = (unsigned short*)w; w += (size_t)N_NODES * HC * 2;
    unsigned short* xb  = (unsigned short*)w; w += (size_t)N_NODES * IN_F * 2;
    unsigned short* h1b = (unsigned short*)w; w += (size_t)N_NODES * C_CH * 2;
    // eah and lah MUST stay contiguous: k_fused indexes eah + e*ED_F for
    // e in [0, EP) -- self-loop rows (e >= N_EDGES) land in lah.
    _Float16* eah = (_Float16*)w;             w += (size_t)N_EDGES * ED_F * 2;
    _Float16* lah = (_Float16*)w;             w += (size_t)N_NODES * ED_F * 2;
    _Float16* weh1T = (_Float16*)w;           w += (size_t)HC * ED_F * 2;
    _Float16* weh2T = (_Float16*)w;           w += (size_t)HC * ED_F * 2;
    unsigned short* Wt1l = (unsigned short*)w; w += (size_t)HC * IN_F * 2;
    unsigned short* Wt1r = (unsigned short*)w; w += (size_t)HC * IN_F * 2;
    unsigned short* Wt2l = (unsigned short*)w; w += (size_t)HC * C_CH * 2;
    unsigned short* Wt2r = (unsigned short*)w; w += (size_t)HC * C_CH * 2;
    // contiguous zero region: deg | cur  (one memset)
    int* deg   = (int*)w;   w += (size_t)N_NODES * 4;
    int* cur   = (int*)w;   w += (size_t)N_NODES * 4;
    int* ptr   = (int*)w;   w += (size_t)(N_NODES + 1) * 4;
    int2* es   = (int2*)w;  w += (size_t)EP * 8;
    int* bsum  = (int*)w;   w += (size_t)(NB_SCAN + 1) * 4;
    int* boff  = (int*)w;   w += (size_t)(NB_SCAN + 1) * 4;

    hipMemsetAsync(deg, 0, (size_t)(2 * N_NODES) * 4, stream);

    // combined casts / weight prep / degree count (one launch)
    k_prep<<<PREP_W_END + 2 + DEG_NB, 256, 0, stream>>>(
        x, xb, ea, eah, Wl1, Wt1l, Wr1, Wt1r, Wl2, Wt2l, Wr2, Wt2r,
        We1, weh1T, We2, weh2T, dstA, deg);

    k_scanA<<<NB_SCAN, 256, 0, stream>>>(deg, ptr, bsum);
    k_scanB<<<1, 64, 0, stream>>>(bsum, boff);
    k_scanC<<<(N_NODES + 256) / 256, 256, 0, stream>>>(ptr, boff);
    k_scatter<<<(EP + 255) / 256, 256, 0, stream>>>(srcA, dstA, ptr, cur, es);
    k_loopattr<<<(N_NODES * ED_F + 255) / 256, 256, 0, stream>>>(ptr, es, ea, deg, lah);

    // layer 1
    dim3 gg((N_NODES + 63) / 64, 4);
    k_gemmM<IN_F><<<gg, 256, 0, stream>>>(xb, Wt1l, bl1, Wt1r, br1, xlh, xrh);
    k_fused<0><<<KF_NB, 256, 0, stream>>>(xlh, xrh, eah, es, ptr, weh1T, att1,
                                          bias1, lng, lnb, h1b, nullptr);
    // layer 2
    k_gemmM<C_CH><<<gg, 256, 0, stream>>>(h1b, Wt2l, bl2, Wt2r, br2, xlh, xrh);
    k_fused<1><<<KF_NB, 256, 0, stream>>>(xlh, xrh, eah, es, ptr, weh2T, att2,
                                          bias2, nullptr, nullptr, nullptr, (float*)d_out);
}

// Round 13
// 317.491 us; speedup vs baseline: 1.0459x; 1.0208x over previous
//
#include <hip/hip_runtime.h>
#include <hip/hip_bf16.h>

// Problem constants (from reference)
#define N_NODES 50000
#define N_EDGES 400000
#define EP (N_EDGES + N_NODES)   // edges incl. self loops = 450000
#define IN_F 128
#define H_HEADS 8
#define C_CH 32
#define HC 256                   // H*C
#define ED_F 16
#define NEG_SLOPE 0.2f
#define LN_EPS 1e-5f
#define NB_SCAN ((N_NODES + 2047) / 2048)   // 25 blocks in phase-A scan
#define NDBINS 1024
#define KF_NB 4096

typedef __hip_bfloat16 bf16;
typedef float v2f __attribute__((ext_vector_type(2)));
typedef short bf16x8 __attribute__((ext_vector_type(8)));
typedef float f32x4 __attribute__((ext_vector_type(4)));
typedef _Float16 h2f __attribute__((ext_vector_type(2)));

__device__ __forceinline__ float bfu(unsigned short v){
    return __uint_as_float((unsigned int)v << 16);
}
__device__ __forceinline__ unsigned short f2b(float v){
    bf16 t = __float2bfloat16(v);
    return *reinterpret_cast<unsigned short*>(&t);
}
__device__ __forceinline__ h2f u2h(unsigned int u){
    union { unsigned int u; h2f h; } x; x.u = u; return x.h;
}

// ---------------- combined input casts / weight prep / degree count (one kernel) ----------------
#define CASTX_NB 3125
#define CASTE_NB 3125
#define W1_NB 128
#define W2_NB 32
#define DEG_NB ((N_EDGES + 255) / 256)
#define PREP_W_END (CASTX_NB + CASTE_NB + 2 * W1_NB + 2 * W2_NB)   // 6570

__device__ __forceinline__ void prepW_body(const float* __restrict__ W,
                                           unsigned short* __restrict__ Wt,
                                           int K, int idx){
    if (idx >= 256 * K) return;
    int c = idx & 255, k = idx >> 8;
    Wt[(size_t)c * K + k] = f2b(W[idx]);
}

__global__ void k_prep(const float* __restrict__ x, unsigned short* __restrict__ xb,
                       const float* __restrict__ ea, _Float16* __restrict__ eah,
                       const float* __restrict__ Wl1, unsigned short* __restrict__ Wt1l,
                       const float* __restrict__ Wr1, unsigned short* __restrict__ Wt1r,
                       const float* __restrict__ Wl2, unsigned short* __restrict__ Wt2l,
                       const float* __restrict__ Wr2, unsigned short* __restrict__ Wt2r,
                       const float* __restrict__ We1, _Float16* __restrict__ weh1T,
                       const float* __restrict__ We2, _Float16* __restrict__ weh2T,
                       const int* __restrict__ dstA, int* __restrict__ deg){
    int b = blockIdx.x, t = threadIdx.x;
    if (b < CASTX_NB){
        int i = b * 256 + t;
        if (i >= N_NODES * IN_F / 8) return;
        const float4* p = reinterpret_cast<const float4*>(x + (size_t)i * 8);
        float4 v0 = p[0], v1 = p[1];
        unsigned short o[8] = {f2b(v0.x), f2b(v0.y), f2b(v0.z), f2b(v0.w),
                               f2b(v1.x), f2b(v1.y), f2b(v1.z), f2b(v1.w)};
        *reinterpret_cast<uint4*>(xb + (size_t)i * 8) = *reinterpret_cast<uint4*>(o);
    } else if (b < CASTX_NB + CASTE_NB){
        int i = (b - CASTX_NB) * 256 + t;     // < 800000 exactly
        const float4* p = reinterpret_cast<const float4*>(ea + (size_t)i * 8);
        float4 v0 = p[0], v1 = p[1];
        _Float16 o[8] = {(_Float16)v0.x, (_Float16)v0.y, (_Float16)v0.z, (_Float16)v0.w,
                         (_Float16)v1.x, (_Float16)v1.y, (_Float16)v1.z, (_Float16)v1.w};
        *reinterpret_cast<uint4*>(eah + (size_t)i * 8) = *reinterpret_cast<uint4*>(o);
    } else if (b < CASTX_NB + CASTE_NB + W1_NB){
        prepW_body(Wl1, Wt1l, IN_F, (b - CASTX_NB - CASTE_NB) * 256 + t);
    } else if (b < CASTX_NB + CASTE_NB + 2 * W1_NB){
        prepW_body(Wr1, Wt1r, IN_F, (b - CASTX_NB - CASTE_NB - W1_NB) * 256 + t);
    } else if (b < CASTX_NB + CASTE_NB + 2 * W1_NB + W2_NB){
        prepW_body(Wl2, Wt2l, C_CH, (b - CASTX_NB - CASTE_NB - 2 * W1_NB) * 256 + t);
    } else if (b < PREP_W_END){
        prepW_body(Wr2, Wt2r, C_CH, (b - CASTX_NB - CASTE_NB - 2 * W1_NB - W2_NB) * 256 + t);
    } else if (b == PREP_W_END){
        // We1^T: weh1T[c][j] = We1[j][c], f16, 16 contiguous per channel
#pragma unroll
        for (int j = 0; j < ED_F; ++j)
            weh1T[t * ED_F + j] = (_Float16)We1[j * HC + t];
    } else if (b == PREP_W_END + 1){
#pragma unroll
        for (int j = 0; j < ED_F; ++j)
            weh2T[t * ED_F + j] = (_Float16)We2[j * HC + t];
    } else {
        // merged k_deg
        int e = (b - PREP_W_END - 2) * 256 + t;
        if (e < N_EDGES) atomicAdd(&deg[dstA[e]], 1);
    }
}

// ---------------- CSR build ----------------
// Degree-balanced ord[] RETAINED (R12 lesson: removing it cost ~5us/dispatch —
// degree-descending order equalizes trip counts of the 4 waves per block, so
// blocks complete tightly; beats the locality gain of natural order).

// scanA + merged degree histogram: bin = NDBINS-1 - min(deg+1, NDBINS-1)
__global__ void k_scanA(const int* __restrict__ deg, int* __restrict__ ptr,
                        int* __restrict__ bsum, int* __restrict__ hist){
    __shared__ int wsum[4];
    __shared__ int lh[NDBINS];
    int blk = blockIdx.x;
    int base0 = blk * 2048;
    int t = threadIdx.x, lane = t & 63, wv = t >> 6;
    for (int j = t; j < NDBINS; j += 256) lh[j] = 0;
    __syncthreads();
    int carry = 0;
    for (int c = 0; c < 8; ++c){
        int i = base0 + c * 256 + t;
        int v = (i < N_NODES) ? (deg[i] + 1) : 0;
        if (i < N_NODES) atomicAdd(&lh[NDBINS - 1 - min(v, NDBINS - 1)], 1);
        int x = v;
#pragma unroll
        for (int off = 1; off < 64; off <<= 1){
            int y = __shfl_up(x, off, 64);
            if (lane >= off) x += y;
        }
        if (lane == 63) wsum[wv] = x;
        __syncthreads();
        int pre = carry;
        for (int j = 0; j < wv; ++j) pre += wsum[j];
        if (i < N_NODES) ptr[i] = pre + x - v;
        int tot = wsum[0] + wsum[1] + wsum[2] + wsum[3];
        __syncthreads();
        carry += tot;
    }
    if (t == 0) bsum[blk] = carry;
    for (int j = t; j < NDBINS; j += 256)
        if (lh[j]) atomicAdd(&hist[j], lh[j]);
}

// merged scanB (boff over 25 block sums) + scanH (hoff over 1024 bins)
__global__ void k_scanBH(const int* __restrict__ bsum, int* __restrict__ boff,
                         const int* __restrict__ hist, int* __restrict__ hoff){
    __shared__ int wsum[4];
    __shared__ int carry_s;
    int t = threadIdx.x, lane = t & 63, wv = t >> 6;
    if (t == 0) carry_s = 0;
    __syncthreads();
    for (int base = 0; base < NDBINS; base += 256){
        int i = base + t;
        int v = hist[i];
        int x = v;
#pragma unroll
        for (int off = 1; off < 64; off <<= 1){
            int y = __shfl_up(x, off, 64);
            if (lane >= off) x += y;
        }
        if (lane == 63) wsum[wv] = x;
        __syncthreads();
        int pre = carry_s;
        for (int j = 0; j < wv; ++j) pre += wsum[j];
        hoff[i] = pre + x - v;
        int tot = wsum[0] + wsum[1] + wsum[2] + wsum[3];
        __syncthreads();
        if (t == 0) carry_s += tot;
        __syncthreads();
    }
    if (t < 64){
        int v = (t < NB_SCAN) ? bsum[t] : 0;
        int x = v;
#pragma unroll
        for (int off = 1; off < 64; off <<= 1){
            int y = __shfl_up(x, off, 64);
            if (t >= off) x += y;
        }
        if (t < NB_SCAN) boff[t] = x - v;
        if (t == 63) boff[NB_SCAN] = x;
    }
}

__global__ void k_scanC(int* __restrict__ ptr, const int* __restrict__ boff){
    int i = blockIdx.x * 256 + threadIdx.x;
    if (i < N_NODES) ptr[i] += boff[i >> 11];
    else if (i == N_NODES) ptr[i] = boff[NB_SCAN];
}

// merged scatter + place: both depend only on final ptr (post-scanC), are
// mutually independent, and write disjoint buffers. blocks [0, PLACE_NB) run
// the degree-balanced counting-sort placement; the rest scatter edges.
#define PLACE_NB ((N_NODES + 255) / 256)
#define SCAT_NB ((EP + 255) / 256)
__global__ void k_scatplace(const int* __restrict__ srcA, const int* __restrict__ dstA,
                            const int* __restrict__ ptr, int* __restrict__ cur,
                            int2* __restrict__ es,
                            const int* __restrict__ hoff, int* __restrict__ hcur,
                            int* __restrict__ ord){
    int t = threadIdx.x;
    if (blockIdx.x < PLACE_NB){
        __shared__ int lh[NDBINS];
        __shared__ int lbase[NDBINS];
        for (int i = t; i < NDBINS; i += 256) lh[i] = 0;
        __syncthreads();
        int n = blockIdx.x * 256 + t;
        int b = -1, lr = 0;
        if (n < N_NODES){
            int d = min(ptr[n + 1] - ptr[n], NDBINS - 1);
            b = NDBINS - 1 - d;
            lr = atomicAdd(&lh[b], 1);
        }
        __syncthreads();
        for (int i = t; i < NDBINS; i += 256)
            if (lh[i]) lbase[i] = atomicAdd(&hcur[i], lh[i]);
        __syncthreads();
        if (n < N_NODES) ord[hoff[b] + lbase[b] + lr] = n;
    } else {
        int e = (blockIdx.x - PLACE_NB) * 256 + t;
        if (e >= EP) return;
        int n, s;
        if (e < N_EDGES){ n = dstA[e]; s = srcA[e]; }
        else            { n = e - N_EDGES; s = n; }
        int p = ptr[n] + atomicAdd(&cur[n], 1);
        es[p] = make_int2(e, s);
    }
}

__global__ void k_loopattr(const int* __restrict__ ptr, const int2* __restrict__ es,
                           const float* __restrict__ ea, const int* __restrict__ deg,
                           _Float16* __restrict__ lah){
    int idx = blockIdx.x * 256 + threadIdx.x;
    if (idx >= N_NODES * ED_F) return;
    int n = idx >> 4, j = idx & 15;
    float s = 0.f;
    int b = ptr[n], t = ptr[n + 1];
    for (int i = b; i < t; ++i){
        int e = es[i].x;
        if (e < N_EDGES) s += ea[(size_t)e * ED_F + j];
    }
    lah[idx] = (_Float16)(s / (float)max(deg[n], 1));
}

// ---------------- MFMA pair GEMM: xl(bf16) = A@Wl + bl, xr(bf16) = A@Wr + br ----------------
// R8 structure (merged-pair variant regressed ~11us: 2x accumulators cut block
// residency; this gemm is occupancy-bound, not A-fetch-bound).
template<int K>
__global__ __launch_bounds__(256)
void k_gemmM(const unsigned short* __restrict__ A,
             const unsigned short* __restrict__ Wtl, const float* __restrict__ bl,
             const unsigned short* __restrict__ Wtr, const float* __restrict__ br,
             bf16* __restrict__ xlh, unsigned short* __restrict__ xrh){
    const int cb = blockIdx.y;            // 0..3: {Wl c0=0, Wl c0=128, Wr c0=0, Wr c0=128}
    const unsigned short* Wt = (cb < 2) ? Wtl : Wtr;
    const float* bs = (cb < 2) ? bl : br;
    const int c0 = (cb & 1) * 128;
    const int r0 = blockIdx.x * 64;

    __shared__ unsigned short sA[64][40];
    __shared__ unsigned short sW[128][40];

    const int tid = threadIdx.x;
    const int lane = tid & 63;
    const int w = tid >> 6;

    f32x4 acc[8] = {};

    for (int kt = 0; kt < K; kt += 32){
        {   // stage A: 64 rows x 32 k
            int row = tid >> 2, kc = (tid & 3) * 8;
            int gr = r0 + row;
            uint4 v = make_uint4(0, 0, 0, 0);
            if (gr < N_NODES)
                v = *reinterpret_cast<const uint4*>(&A[(size_t)gr * K + kt + kc]);
            *reinterpret_cast<uint4*>(&sA[row][kc]) = v;
        }
        {   // stage W: 128 cols x 32 k
            int c = tid >> 1, kc = (tid & 1) * 16;
            const unsigned short* src = &Wt[(size_t)(c0 + c) * K + kt + kc];
            *reinterpret_cast<uint4*>(&sW[c][kc])     = *reinterpret_cast<const uint4*>(src);
            *reinterpret_cast<uint4*>(&sW[c][kc + 8]) = *reinterpret_cast<const uint4*>(src + 8);
        }
        __syncthreads();
        int kchunk = (lane >> 4) * 8;
        bf16x8 af = *reinterpret_cast<const bf16x8*>(&sA[w * 16 + (lane & 15)][kchunk]);
#pragma unroll
        for (int f = 0; f < 8; ++f){
            bf16x8 bfr = *reinterpret_cast<const bf16x8*>(&sW[f * 16 + (lane & 15)][kchunk]);
            acc[f] = __builtin_amdgcn_mfma_f32_16x16x32_bf16(af, bfr, acc[f], 0, 0, 0);
        }
        __syncthreads();
    }
    int colL = lane & 15;
    int rbase = (lane >> 4) * 4;
#pragma unroll
    for (int f = 0; f < 8; ++f){
        int col = c0 + f * 16 + colL;
        float bv = bs[col];
#pragma unroll
        for (int r = 0; r < 4; ++r){
            int gr = r0 + w * 16 + rbase + r;
            if (gr < N_NODES){
                float ov = acc[f][r] + bv;
                if (cb < 2) xlh[(size_t)gr * HC + col] = __float2bfloat16(ov);
                else        xrh[(size_t)gr * HC + col] = f2b(ov);
            }
        }
    }
}

// ---------------- fused per-node: logits + softmax + aggregate + epilogue ----------------
// R8 EXACT (best measured: 93.6us/dispatch, VGPR=48, occ 46%): f16 We via
// fdot2, scalar-uniform metadata (SMEM es + SALU control), batch-4 loop,
// degree-ordered ord[] (equalizes per-block wave trip counts).
// CLOSED LEVERS (do not retry): batch-8 (R9), depth-2 pipeline (R10),
// occupancy attrs (R2/R7), ord removal (R12), gemm pair-merge (R11).
// MODE 0: layer 1 -> relu + layernorm -> h1 (bf16);  MODE 1: layer 2 -> f32 output
template<int MODE>
__global__ __launch_bounds__(256)
__attribute__((amdgpu_waves_per_eu(4, 8)))
void k_fused(const bf16* __restrict__ xlh, const unsigned short* __restrict__ xrh,
             const _Float16* __restrict__ eah,
             const int2* __restrict__ es, const int* __restrict__ ptr,
             const int* __restrict__ ord,
             const _Float16* __restrict__ wehT, const float* __restrict__ att,
             const float* __restrict__ bias, const float* __restrict__ lng,
             const float* __restrict__ lnb,
             unsigned short* __restrict__ h1b, float* __restrict__ outF){
    const int wv = threadIdx.x >> 6;
    const int lane = threadIdx.x & 63;
    const int c0 = lane * 4;
    const int k = lane & 7;

    // wave-invariant: We column slice in f16 pairs (32 VGPRs) + att slice
    h2f wh[4][8];
#pragma unroll
    for (int c = 0; c < 4; ++c){
        uint4 wa = *reinterpret_cast<const uint4*>(wehT + (size_t)(c0 + c) * ED_F);
        uint4 wb = *reinterpret_cast<const uint4*>(wehT + (size_t)(c0 + c) * ED_F + 8);
        wh[c][0] = u2h(wa.x); wh[c][1] = u2h(wa.y); wh[c][2] = u2h(wa.z); wh[c][3] = u2h(wa.w);
        wh[c][4] = u2h(wb.x); wh[c][5] = u2h(wb.y); wh[c][6] = u2h(wb.z); wh[c][7] = u2h(wb.w);
    }
    float4 at4 = *reinterpret_cast<const float4*>(att + c0);
    // fold ln2-conversion into att: exp(z.att) == exp2(z.(att*log2e))
    at4.x *= 1.44269504f; at4.y *= 1.44269504f; at4.z *= 1.44269504f; at4.w *= 1.44269504f;

#define EDGE_MLP(PK, AR, U)                                               \
        {                                                                 \
            uint4 ua = *reinterpret_cast<const uint4*>(AR);               \
            uint4 ub = *reinterpret_cast<const uint4*>(AR + 8);           \
            h2f eh_[8] = {u2h(ua.x), u2h(ua.y), u2h(ua.z), u2h(ua.w),     \
                          u2h(ub.x), u2h(ub.y), u2h(ub.z), u2h(ub.w)};    \
            float z0 = bfu(U.x) + xr0, z1 = bfu(U.y) + xr1;               \
            float z2 = bfu(U.z) + xr2, z3 = bfu(U.w) + xr3;               \
            _Pragma("unroll")                                             \
            for (int j2 = 0; j2 < 8; ++j2){                               \
                z0 = __builtin_amdgcn_fdot2(eh_[j2], wh[0][j2], z0, false);\
                z1 = __builtin_amdgcn_fdot2(eh_[j2], wh[1][j2], z1, false);\
                z2 = __builtin_amdgcn_fdot2(eh_[j2], wh[2][j2], z2, false);\
                z3 = __builtin_amdgcn_fdot2(eh_[j2], wh[3][j2], z3, false);\
            }                                                             \
            z0 = fmaxf(z0, NEG_SLOPE * z0);                               \
            z1 = fmaxf(z1, NEG_SLOPE * z1);                               \
            z2 = fmaxf(z2, NEG_SLOPE * z2);                               \
            z3 = fmaxf(z3, NEG_SLOPE * z3);                               \
            PK = z0 * at4.x + z1 * at4.y + z2 * at4.z + z3 * at4.w;       \
        }

    const int nw = KF_NB * 4;
    for (int idx = blockIdx.x * 4 + wv; idx < N_NODES; idx += nw){
        // scalar-uniform node metadata: SMEM es loads + SALU loop control
        int n = __builtin_amdgcn_readfirstlane(ord[idx]);
        int b = __builtin_amdgcn_readfirstlane(ptr[n]);
        int tend = __builtin_amdgcn_readfirstlane(ptr[n + 1]);

        ushort4 xu = *reinterpret_cast<const ushort4*>(xrh + (size_t)n * HC + c0);
        float xr0 = bfu(xu.x), xr1 = bfu(xu.y), xr2 = bfu(xu.z), xr3 = bfu(xu.w);

        float ssum = 0.f;
        v2f accv[2] = {v2f{0.f, 0.f}, v2f{0.f, 0.f}};

        int i = b;
        // ---- full batches of 4: no clamping, no predication ----
        for (; i + 4 <= tend; i += 4){
            int2 q0 = es[i], q1 = es[i + 1], q2 = es[i + 2], q3 = es[i + 3];
            int e0 = __builtin_amdgcn_readfirstlane(q0.x);
            int s0 = __builtin_amdgcn_readfirstlane(q0.y);
            int e1 = __builtin_amdgcn_readfirstlane(q1.x);
            int s1 = __builtin_amdgcn_readfirstlane(q1.y);
            int e2 = __builtin_amdgcn_readfirstlane(q2.x);
            int s2 = __builtin_amdgcn_readfirstlane(q2.y);
            int e3 = __builtin_amdgcn_readfirstlane(q3.x);
            int s3 = __builtin_amdgcn_readfirstlane(q3.y);
            const _Float16* ar0 = eah + (size_t)e0 * ED_F;
            const _Float16* ar1 = eah + (size_t)e1 * ED_F;
            const _Float16* ar2 = eah + (size_t)e2 * ED_F;
            const _Float16* ar3 = eah + (size_t)e3 * ED_F;

            ushort4 u0 = *reinterpret_cast<const ushort4*>(xlh + (size_t)s0 * HC + c0);
            ushort4 u1 = *reinterpret_cast<const ushort4*>(xlh + (size_t)s1 * HC + c0);
            ushort4 u2 = *reinterpret_cast<const ushort4*>(xlh + (size_t)s2 * HC + c0);
            ushort4 u3 = *reinterpret_cast<const ushort4*>(xlh + (size_t)s3 * HC + c0);

            float p0, p1, p2, p3;
            EDGE_MLP(p0, ar0, u0)
            EDGE_MLP(p1, ar1, u1)
            EDGE_MLP(p2, ar2, u2)
            EDGE_MLP(p3, ar3, u3)

            p0 += __shfl_xor(p0, 1, 64); p1 += __shfl_xor(p1, 1, 64);
            p2 += __shfl_xor(p2, 1, 64); p3 += __shfl_xor(p3, 1, 64);
            p0 += __shfl_xor(p0, 2, 64); p1 += __shfl_xor(p1, 2, 64);
            p2 += __shfl_xor(p2, 2, 64); p3 += __shfl_xor(p3, 2, 64);
            p0 += __shfl_xor(p0, 4, 64); p1 += __shfl_xor(p1, 4, 64);
            p2 += __shfl_xor(p2, 4, 64); p3 += __shfl_xor(p3, 4, 64);

            float w0 = __builtin_amdgcn_exp2f(p0);
            float w1 = __builtin_amdgcn_exp2f(p1);
            float w2 = __builtin_amdgcn_exp2f(p2);
            float w3 = __builtin_amdgcn_exp2f(p3);
            ssum += w0 + w1 + w2 + w3;
            v2f w0v = {w0, w0}, w1v = {w1, w1}, w2v = {w2, w2}, w3v = {w3, w3};
            accv[0] += w0v * v2f{bfu(u0.x), bfu(u0.y)} + w1v * v2f{bfu(u1.x), bfu(u1.y)}
                     + w2v * v2f{bfu(u2.x), bfu(u2.y)} + w3v * v2f{bfu(u3.x), bfu(u3.y)};
            accv[1] += w0v * v2f{bfu(u0.z), bfu(u0.w)} + w1v * v2f{bfu(u1.z), bfu(u1.w)}
                     + w2v * v2f{bfu(u2.z), bfu(u2.w)} + w3v * v2f{bfu(u3.z), bfu(u3.w)};
        }
        // ---- exact remainder (0..3 edges) ----
        for (; i < tend; ++i){
            int2 q0 = es[i];
            int e0 = __builtin_amdgcn_readfirstlane(q0.x);
            int s0 = __builtin_amdgcn_readfirstlane(q0.y);
            const _Float16* ar0 = eah + (size_t)e0 * ED_F;
            ushort4 u0 = *reinterpret_cast<const ushort4*>(xlh + (size_t)s0 * HC + c0);
            float p0;
            EDGE_MLP(p0, ar0, u0)
            p0 += __shfl_xor(p0, 1, 64);
            p0 += __shfl_xor(p0, 2, 64);
            p0 += __shfl_xor(p0, 4, 64);
            float w0 = __builtin_amdgcn_exp2f(p0);
            ssum += w0;
            v2f w0v = {w0, w0};
            accv[0] += w0v * v2f{bfu(u0.x), bfu(u0.y)};
            accv[1] += w0v * v2f{bfu(u0.z), bfu(u0.w)};
        }

        float inv = __builtin_amdgcn_rcpf(ssum + 1e-16f);
        float acc[4] = {accv[0].x * inv, accv[0].y * inv, accv[1].x * inv, accv[1].y * inv};
#pragma unroll
        for (int q = 0; q < 4; ++q){
            acc[q] += __shfl_xor(acc[q], 8, 64);
            acc[q] += __shfl_xor(acc[q], 16, 64);
            acc[q] += __shfl_xor(acc[q], 32, 64);
        }
        float val[4];
#pragma unroll
        for (int q = 0; q < 4; ++q) val[q] = acc[q] * 0.125f + bias[k * 4 + q];

        if (MODE == 0){
            float r[4], s1 = 0.f, s2 = 0.f;
#pragma unroll
            for (int q = 0; q < 4; ++q){ r[q] = fmaxf(val[q], 0.f); s1 += r[q]; s2 += r[q] * r[q]; }
#pragma unroll
            for (int msk = 1; msk <= 4; msk <<= 1){
                s1 += __shfl_xor(s1, msk, 64);
                s2 += __shfl_xor(s2, msk, 64);
            }
            float mu = s1 * (1.f / 32.f);
            float var = s2 * (1.f / 32.f) - mu * mu;
            float rinv = rsqrtf(var + LN_EPS);
            if (lane < 8){
                unsigned short o[4];
#pragma unroll
                for (int q = 0; q < 4; ++q)
                    o[q] = f2b((r[q] - mu) * rinv * lng[k * 4 + q] + lnb[k * 4 + q]);
                *reinterpret_cast<ushort4*>(h1b + (size_t)n * C_CH + k * 4) =
                    *reinterpret_cast<ushort4*>(o);
            }
        } else {
            if (lane < 8){
                *reinterpret_cast<float4*>(outF + (size_t)n * C_CH + k * 4) =
                    make_float4(val[0], val[1], val[2], val[3]);
            }
        }
    }
#undef EDGE_MLP
}

// ---------------- launch ----------------

extern "C" void kernel_launch(void* const* d_in, const int* in_sizes, int n_in,
                              void* d_out, int out_size, void* d_ws, size_t ws_size,
                              hipStream_t stream){
    const float* x    = (const float*)d_in[0];
    const int*   ei   = (const int*)d_in[1];
    const float* ea   = (const float*)d_in[2];
    const float* Wl1  = (const float*)d_in[3];
    const float* bl1  = (const float*)d_in[4];
    const float* Wr1  = (const float*)d_in[5];
    const float* br1  = (const float*)d_in[6];
    const float* We1  = (const float*)d_in[7];
    const float* att1 = (const float*)d_in[8];
    const float* bias1= (const float*)d_in[9];
    const float* Wl2  = (const float*)d_in[10];
    const float* bl2  = (const float*)d_in[11];
    const float* Wr2  = (const float*)d_in[12];
    const float* br2  = (const float*)d_in[13];
    const float* We2  = (const float*)d_in[14];
    const float* att2 = (const float*)d_in[15];
    const float* bias2= (const float*)d_in[16];
    const float* lng  = (const float*)d_in[17];
    const float* lnb  = (const float*)d_in[18];
    const int* srcA = ei;
    const int* dstA = ei + N_EDGES;

    // workspace layout (~95 MB)
    char* w = (char*)d_ws;
    bf16*  xlh = (bf16*)w;                    w += (size_t)N_NODES * HC * 2;
    unsigned short* xrh = (unsigned short*)w; w += (size_t)N_NODES * HC * 2;
    unsigned short* xb  = (unsigned short*)w; w += (size_t)N_NODES * IN_F * 2;
    unsigned short* h1b = (unsigned short*)w; w += (size_t)N_NODES * C_CH * 2;
    // eah and lah MUST stay contiguous: k_fused indexes eah + e*ED_F for
    // e in [0, EP) -- self-loop rows (e >= N_EDGES) land in lah.
    _Float16* eah = (_Float16*)w;             w += (size_t)N_EDGES * ED_F * 2;
    _Float16* lah = (_Float16*)w;             w += (size_t)N_NODES * ED_F * 2;
    _Float16* weh1T = (_Float16*)w;           w += (size_t)HC * ED_F * 2;
    _Float16* weh2T = (_Float16*)w;           w += (size_t)HC * ED_F * 2;
    unsigned short* Wt1l = (unsigned short*)w; w += (size_t)HC * IN_F * 2;
    unsigned short* Wt1r = (unsigned short*)w; w += (size_t)HC * IN_F * 2;
    unsigned short* Wt2l = (unsigned short*)w; w += (size_t)HC * C_CH * 2;
    unsigned short* Wt2r = (unsigned short*)w; w += (size_t)HC * C_CH * 2;
    // contiguous zero region: deg | cur | hist | hcur  (one memset)
    int* deg   = (int*)w;   w += (size_t)N_NODES * 4;
    int* cur   = (int*)w;   w += (size_t)N_NODES * 4;
    int* hist  = (int*)w;   w += (size_t)NDBINS * 4;
    int* hcur  = (int*)w;   w += (size_t)NDBINS * 4;
    int* ptr   = (int*)w;   w += (size_t)(N_NODES + 1) * 4;
    int2* es   = (int2*)w;  w += (size_t)EP * 8;
    int* bsum  = (int*)w;   w += (size_t)(NB_SCAN + 1) * 4;
    int* boff  = (int*)w;   w += (size_t)(NB_SCAN + 1) * 4;
    int* hoff  = (int*)w;   w += (size_t)NDBINS * 4;
    int* ord   = (int*)w;   w += (size_t)N_NODES * 4;

    hipMemsetAsync(deg, 0, (size_t)(2 * N_NODES + 2 * NDBINS) * 4, stream);

    // combined casts / weight prep / degree count (one launch)
    k_prep<<<PREP_W_END + 2 + DEG_NB, 256, 0, stream>>>(
        x, xb, ea, eah, Wl1, Wt1l, Wr1, Wt1r, Wl2, Wt2l, Wr2, Wt2r,
        We1, weh1T, We2, weh2T, dstA, deg);

    k_scanA<<<NB_SCAN, 256, 0, stream>>>(deg, ptr, bsum, hist);
    k_scanBH<<<1, 256, 0, stream>>>(bsum, boff, hist, hoff);
    k_scanC<<<(N_NODES + 256) / 256, 256, 0, stream>>>(ptr, boff);
    k_scatplace<<<PLACE_NB + SCAT_NB, 256, 0, stream>>>(srcA, dstA, ptr, cur, es,
                                                        hoff, hcur, ord);
    k_loopattr<<<(N_NODES * ED_F + 255) / 256, 256, 0, stream>>>(ptr, es, ea, deg, lah);

    // layer 1
    dim3 gg((N_NODES + 63) / 64, 4);
    k_gemmM<IN_F><<<gg, 256, 0, stream>>>(xb, Wt1l, bl1, Wt1r, br1, xlh, xrh);
    k_fused<0><<<KF_NB, 256, 0, stream>>>(xlh, xrh, eah, es, ptr, ord, weh1T, att1,
                                          bias1, lng, lnb, h1b, nullptr);
    // layer 2
    k_gemmM<C_CH><<<gg, 256, 0, stream>>>(h1b, Wt2l, bl2, Wt2r, br2, xlh, xrh);
    k_fused<1><<<KF_NB, 256, 0, stream>>>(xlh, xrh, eah, es, ptr, ord, weh2T, att2,
                                          bias2, nullptr, nullptr, nullptr, (float*)d_out);
}